// Round 10
// baseline (566.408 us; speedup 1.0000x reference)
//
#include <hip/hip_runtime.h>
#include <cstdint>
#include <cstddef>
#include <cmath>

#define D 128
#define SLOTS 32          // padded CSR slots per node (mean deg = 8)
#define SPILL_CAP 65536   // overflow edges (deg>32): P ~ 1e-5 for this input

typedef short bf16x8 __attribute__((ext_vector_type(8)));
typedef float f32x4 __attribute__((ext_vector_type(4)));

__device__ __forceinline__ ushort f2b(float f) {
  uint x = __float_as_uint(f);
  uint r = ((x >> 16) & 1u) + 0x7fffu;   // round-to-nearest-even
  return (ushort)((x + r) >> 16);
}
__device__ __forceinline__ float b2f(ushort u) {
  return __uint_as_float(((uint)u) << 16);
}

// global -> LDS direct DMA, 16B per lane; HW writes lane l at lds_base + l*16
__device__ __forceinline__ void gl2lds16(const void* g, void* l) {
  __builtin_amdgcn_global_load_lds(
      (__attribute__((address_space(1))) void*)const_cast<void*>(g),
      (__attribute__((address_space(3))) void*)l, 16, 0, 0);
}

// ========== ONE-PASS padded CSR fill (XCD-partitioned) + conv + pack =========
// Replaces the degree/scan/scan/fill pipeline (4 dispatches -> 1).
// blocks [0,768): partitioned fill -- partition p owns d in [pN/8,(p+1)N/8);
// atomics target a compact 50KB cnt range per partition (r7/r9 A/B showed
// cross-XCD scattered atomics cost ~+30us). pos<32 -> fixed slot write;
// overflow -> spill list (exactness preserved; practically never taken).
// [768,768+cb): x fp32->bf16. Rest: weight pack. All independent -> overlap.
__global__ __launch_bounds__(256) void k_fill_conv(
    const int* __restrict__ src, const int* __restrict__ dst, int E,
    int* __restrict__ cnt, int* __restrict__ csrc,
    int* __restrict__ spillc, int* __restrict__ spill_d, int* __restrict__ spill_s,
    float scale, int CE,
    const float* __restrict__ in, ushort* __restrict__ outx, int n8, int cb,
    const float* __restrict__ Ws0, const float* __restrict__ Wn0,
    const float* __restrict__ Ws1, const float* __restrict__ Wn1,
    const float* __restrict__ Ws2, const float* __restrict__ Wn2,
    const float* __restrict__ Wp0, const float* __restrict__ Wp1,
    ushort* __restrict__ BpL0, ushort* __restrict__ BpL1, ushort* __restrict__ BpL2,
    ushort* __restrict__ BpP0, ushort* __restrict__ BpP1) {
  int b = blockIdx.x;
  if (b < 768) {
    int part = b & 7, chunk = b >> 3;
    long base = (long)chunk * CE;
    for (int i = threadIdx.x; i < CE; i += 256) {
      long e = base + i;
      if (e < E) {
        int d = dst[e];
        int p = (int)((float)d * scale); if (p > 7) p = 7;
        if (p == part) {
          int s = src[e];
          int pos = atomicAdd(&cnt[d], 1);
          if (pos < SLOTS) {
            csrc[((size_t)d << 5) + pos] = s;
          } else {
            int si = atomicAdd(spillc, 1);
            if (si < SPILL_CAP) { spill_d[si] = d; spill_s[si] = s; }
          }
        }
      }
    }
    return;
  }
  int b2 = b - 768;
  if (b2 < cb) {
    int i = b2 * 256 + threadIdx.x;
    if (i >= n8) return;
    float4 a = ((const float4*)in)[i * 2];
    float4 c = ((const float4*)in)[i * 2 + 1];
    ushort4 o0 = {f2b(a.x), f2b(a.y), f2b(a.z), f2b(a.w)};
    ushort4 o1 = {f2b(c.x), f2b(c.y), f2b(c.z), f2b(c.w)};
    ((ushort4*)outx)[i * 2] = o0;
    ((ushort4*)outx)[i * 2 + 1] = o1;
    return;
  }
  int o = (b2 - cb) * 256 + threadIdx.x;   // total 131072
  const float *W0, *W1; ushort* outp; int rel;
  if (o < 32768)       { W0 = Ws0; W1 = Wn0; outp = BpL0; rel = o; }
  else if (o < 65536)  { W0 = Ws1; W1 = Wn1; outp = BpL1; rel = o - 32768; }
  else if (o < 98304)  { W0 = Ws2; W1 = Wn2; outp = BpL2; rel = o - 65536; }
  else if (o < 114688) { W0 = Wp0; W1 = Wp0; outp = BpP0; rel = o - 98304; }
  else                 { W0 = Wp1; W1 = Wp1; outp = BpP1; rel = o - 114688; }
  int j = rel & 7, lane = (rel >> 3) & 63, t = (rel >> 9) & 7, ks = rel >> 12;
  int k = ks * 32 + ((lane >> 4) * 8) + j;
  int n = t * 16 + (lane & 15);
  const float* W = (k < 128) ? W0 : W1;
  int kk = (k < 128) ? k : k - 128;
  outp[rel] = f2b(W[(size_t)kk * D + n]);
}

// ======================= fused aggregate + SAGE GEMM =======================
// Gather core = r7/r9 proven version (61.5-63us band): (128,4), plain stores,
// unroll-4 unconditional 16-load clusters, pipelined clamped offset shuffles,
// {0,1}-weight fmac, wave-local smean handoff. Phase A now reads cnt[node] +
// fixed-stride padded slots (no rowptr). Exact deg>SLOTS handling via spill
// scan (practically never taken).
#define SMS 136
__global__ __launch_bounds__(128, 4) void k_sage_fused(
    const ushort* __restrict__ A, const int* __restrict__ cnt,
    const int* __restrict__ csrc,
    const int* __restrict__ spillc, const int* __restrict__ spill_d,
    const int* __restrict__ spill_s, const ushort* __restrict__ Bp,
    const float* __restrict__ bias, ushort* __restrict__ out, int N, int do_relu) {
  __shared__ __align__(16) ushort smean[2][16][SMS];   // 8704 B
  int tid = threadIdx.x, wave = tid >> 6, lane = tid & 63;
  int m = lane & 15, kg = lane >> 4;        // MFMA roles
  int g = kg, sub = m;                      // gather roles: 4 groups of 16
  int gb = g << 4;                          // group base lane
  int row0 = (blockIdx.x * 2 + wave) * 16;  // this wave's 16-row tile
  uint hbo = (uint)(sub * 16);              // byte offset of this lane's 16B slice

  // ---- phase A: per-node counts + edge-index prefetch (padded slots) ----
  int node0 = row0 + g * 4;
  int cv = 0;
  if (sub < 4) { int ix = node0 + sub; if (ix < N) cv = cnt[ix]; }
  int dgf[4], dd[4];
  #pragma unroll
  for (int j = 0; j < 4; ++j) {
    dgf[j] = __shfl(cv, gb + j);
    dd[j] = dgf[j] < 16 ? dgf[j] : 16;
  }
  int idxv[4];
  #pragma unroll
  for (int j = 0; j < 4; ++j) {
    idxv[j] = (sub < dgf[j]) ? csrc[((size_t)(uint)(node0 + j) << 5) + sub] : 0;
  }

  // ---- phase B: unroll-4 gather, unconditional 16-load clusters ----
  float f[4][8];
  #pragma unroll
  for (int j = 0; j < 4; ++j)
    #pragma unroll
    for (int q = 0; q < 8; ++q) f[j][q] = 0.f;

  int maxdd = dd[0];
  if (dd[1] > maxdd) maxdd = dd[1];
  if (dd[2] > maxdd) maxdd = dd[2];
  if (dd[3] > maxdd) maxdd = dd[3];

  uint off[4][4];
  #pragma unroll
  for (int j = 0; j < 4; ++j)
    #pragma unroll
    for (int k = 0; k < 4; ++k)
      off[j][k] = hbo + ((uint)__shfl(idxv[j], gb + k) << 8);

  #pragma unroll 1
  for (int e = 0; e < maxdd; e += 4) {
    bf16x8 r[4][4];
    #pragma unroll
    for (int j = 0; j < 4; ++j)
      #pragma unroll
      for (int k = 0; k < 4; ++k)
        r[j][k] = *(const bf16x8*)((const char*)A + off[j][k]);
    __builtin_amdgcn_sched_barrier(0);
    #pragma unroll
    for (int j = 0; j < 4; ++j)
      #pragma unroll
      for (int k = 0; k < 4; ++k) {
        int sl = e + 4 + k; sl = (sl > 15) ? 15 : sl;
        off[j][k] = hbo + ((uint)__shfl(idxv[j], gb + sl) << 8);
      }
    __builtin_amdgcn_sched_barrier(0);
    #pragma unroll
    for (int j = 0; j < 4; ++j) {
      #pragma unroll
      for (int k = 0; k < 4; ++k) {
        float w = (e + k < dd[j]) ? 1.0f : 0.0f;
        #pragma unroll
        for (int q = 0; q < 8; ++q) f[j][q] += w * b2f((ushort)r[j][k][q]);
      }
    }
  }
  // rare deg>16 tail: slots 16..min(deg,SLOTS)
  #pragma unroll
  for (int j = 0; j < 4; ++j) {
    int nd = node0 + j;
    int lim = dgf[j] < SLOTS ? dgf[j] : SLOTS;
    for (int i = 16; i < lim; ++i) {
      int s = csrc[((size_t)(uint)nd << 5) + i];
      bf16x8 v = *(const bf16x8*)((const char*)A + (hbo + ((uint)s << 8)));
      #pragma unroll
      for (int q = 0; q < 8; ++q) f[j][q] += b2f((ushort)v[q]);
    }
    // exact deg>SLOTS fallback: scan the (practically empty) spill list
    if (dgf[j] > SLOTS) {
      int sc = *spillc; if (sc > SPILL_CAP) sc = SPILL_CAP;
      for (int i = 0; i < sc; ++i) {
        if (spill_d[i] == nd) {
          int s = spill_s[i];
          bf16x8 v = *(const bf16x8*)((const char*)A + (hbo + ((uint)s << 8)));
          #pragma unroll
          for (int q = 0; q < 8; ++q) f[j][q] += b2f((ushort)v[q]);
        }
      }
    }
  }
  #pragma unroll
  for (int j = 0; j < 4; ++j) {
    float inv = (dgf[j] > 0) ? (1.0f / (float)dgf[j]) : 0.0f;
    bf16x8 o;
    #pragma unroll
    for (int q = 0; q < 8; ++q) o[q] = (short)f2b(f[j][q] * inv);
    *(bf16x8*)&smean[wave][g * 4 + j][sub * 8] = o;
  }
  asm volatile("s_waitcnt lgkmcnt(0)" ::: "memory");
  __builtin_amdgcn_sched_barrier(0);

  // ---- MFMA phase ----
  int ar = row0 + m; if (ar >= N) ar = N - 1;
  const ushort* a_self = A + (size_t)ar * D + kg * 8;
  f32x4 acc[8];
  #pragma unroll
  for (int t = 0; t < 8; ++t) acc[t] = f32x4{0.f, 0.f, 0.f, 0.f};
  #pragma unroll
  for (int ks = 0; ks < 8; ++ks) {
    bf16x8 af = (ks < 4) ? *(const bf16x8*)(a_self + ks * 32)
                         : *(const bf16x8*)&smean[wave][m][(ks - 4) * 32 + kg * 8];
    const ushort* bb = Bp + (size_t)ks * 4096 + lane * 8;
    #pragma unroll
    for (int t = 0; t < 8; ++t)
      acc[t] = __builtin_amdgcn_mfma_f32_16x16x32_bf16(af, *(const bf16x8*)(bb + t * 512), acc[t], 0, 0, 0);
  }
  #pragma unroll
  for (int t = 0; t < 8; ++t) {
    int c = t * 16 + m;
    float bv = bias[c];
    #pragma unroll
    for (int i = 0; i < 4; ++i) {
      int r = row0 + kg * 4 + i;
      float v = acc[t][i] + bv;
      if (do_relu) v = fmaxf(v, 0.f);
      if (r < N) out[(size_t)r * D + c] = f2b(v);
    }
  }
}

// ======================= fused predictor MLP (DMA-staged gathers) ==============
__global__ __launch_bounds__(256, 5) void k_predict_mfma(
    const ushort* __restrict__ h,
    const int* __restrict__ ps, const int* __restrict__ pd,
    const int* __restrict__ ns, const int* __restrict__ nd,
    const ushort* __restrict__ Bp0, const float* __restrict__ bp0,
    const ushort* __restrict__ Bp1, const float* __restrict__ bp1,
    const float* __restrict__ Wp2, const float* __restrict__ bp2,
    float* __restrict__ outp, int P, int pb) {
  __shared__ __align__(1024) ushort slab[4][4096];  // 8KB/wave: hs @0, hd @4KB
  int bi = blockIdx.x;
  const int* sidx; const int* didx; float* op;
  if (bi >= pb) { sidx = ns; didx = nd; op = outp + P; bi -= pb; }
  else          { sidx = ps; didx = pd; op = outp; }
  int tid = threadIdx.x;
  int wave = tid >> 6, lane = tid & 63;
  int m = lane & 15, kg = lane >> 4;
  int pair0 = bi * 64 + wave * 16;
  int prow = pair0 + m; int pr = (prow < P) ? prow : P - 1;
  int si = sidx[pr], di = didx[pr];    // lane m holds pair m (kg-duplicated)
  char* sl = (char*)&slab[wave][0];

  // ---- stage: instr q covers rows q*4+(lane>>4); lane l writes LDS at +l*16.
  // source slice = (l&15) ^ (row&7)  => LDS slot c of row r holds slice c^(r&7)
  {
    int rsub = lane >> 4;
    #pragma unroll
    for (int q = 0; q < 4; ++q) {
      int rr = q * 4 + rsub;
      int ir = __shfl(si, rr);
      const char* g = (const char*)h + ((size_t)(uint)ir << 8)
                      + (uint)((((lane & 15) ^ (rr & 7)) << 4));
      gl2lds16(g, sl + (q << 10));
    }
    #pragma unroll
    for (int q = 0; q < 4; ++q) {
      int rr = q * 4 + rsub;
      int ir = __shfl(di, rr);
      const char* g = (const char*)h + ((size_t)(uint)ir << 8)
                      + (uint)((((lane & 15) ^ (rr & 7)) << 4));
      gl2lds16(g, sl + 4096 + (q << 10));
    }
  }
  __syncthreads();   // compiler drains vmcnt(0) before barrier (m97 semantics)

  f32x4 acc[8];
  #pragma unroll
  for (int t = 0; t < 8; ++t) acc[t] = f32x4{0.f, 0.f, 0.f, 0.f};
  // ---- GEMM1: z = hs*hd ; acc = z @ Wp0 (swizzled LDS reads) ----
  #pragma unroll
  for (int ks = 0; ks < 4; ++ks) {
    int slot = (ks * 4 + kg) ^ (m & 7);
    const char* rbase = sl + m * 256 + slot * 16;
    bf16x8 as8 = *(const bf16x8*)rbase;
    bf16x8 ad8 = *(const bf16x8*)(rbase + 4096);
    bf16x8 af;
    #pragma unroll
    for (int j = 0; j < 8; ++j) {
      float p = b2f((ushort)as8[j]) * b2f((ushort)ad8[j]);
      af[j] = (short)f2b(p);
    }
    const ushort* bb = Bp0 + (size_t)ks * 4096 + lane * 8;
    #pragma unroll
    for (int t = 0; t < 8; ++t)
      acc[t] = __builtin_amdgcn_mfma_f32_16x16x32_bf16(af, *(const bf16x8*)(bb + t * 512), acc[t], 0, 0, 0);
  }
  // ---- epilogue1: relu(acc + bp0) -> z1p (overlays consumed hs region) ----
  ushort* zp = (ushort*)sl;
  #pragma unroll
  for (int t = 0; t < 8; ++t) {
    int c = t * 16 + m;
    float bv = bp0[c];
    int ks2 = c >> 5, kg2 = (c >> 3) & 3, j2 = c & 7;
    #pragma unroll
    for (int i = 0; i < 4; ++i) {
      float v = fmaxf(acc[t][i] + bv, 0.f);
      int l2 = kg2 * 16 + kg * 4 + i;     // consumer lane
      zp[(ks2 * 64 + l2) * 8 + j2] = f2b(v);
    }
  }
  // wave-local handoff (slab written and read by THIS wave only)
  asm volatile("s_waitcnt lgkmcnt(0)" ::: "memory");
  __builtin_amdgcn_sched_barrier(0);
  // ---- GEMM2: acc = z1 @ Wp1 ----
  #pragma unroll
  for (int t = 0; t < 8; ++t) acc[t] = f32x4{0.f, 0.f, 0.f, 0.f};
  #pragma unroll
  for (int ks = 0; ks < 4; ++ks) {
    bf16x8 af = *(const bf16x8*)(zp + (ks * 64 + lane) * 8);
    const ushort* bb = Bp1 + (size_t)ks * 4096 + lane * 8;
    #pragma unroll
    for (int t = 0; t < 8; ++t)
      acc[t] = __builtin_amdgcn_mfma_f32_16x16x32_bf16(af, *(const bf16x8*)(bb + t * 512), acc[t], 0, 0, 0);
  }
  // ---- final: z2 = relu(acc + bp1); logits = z2 @ Wp2 + bp2; sigmoid ----
  float p0[4] = {0.f, 0.f, 0.f, 0.f}, p1[4] = {0.f, 0.f, 0.f, 0.f};
  #pragma unroll
  for (int t = 0; t < 8; ++t) {
    int c = t * 16 + m;
    float bv = bp1[c];
    float wa = Wp2[(size_t)c * 2], wb = Wp2[(size_t)c * 2 + 1];
    #pragma unroll
    for (int i = 0; i < 4; ++i) {
      float z = fmaxf(acc[t][i] + bv, 0.f);
      p0[i] += z * wa;
      p1[i] += z * wb;
    }
  }
  #pragma unroll
  for (int msk = 1; msk <= 8; msk <<= 1) {
    #pragma unroll
    for (int i = 0; i < 4; ++i) {
      p0[i] += __shfl_xor(p0[i], msk);
      p1[i] += __shfl_xor(p1[i], msk);
    }
  }
  if (m == 0) {
    float c0 = bp2[0], c1 = bp2[1];
    #pragma unroll
    for (int i = 0; i < 4; ++i) {
      int r = pair0 + kg * 4 + i;
      if (r < P) {
        float l0 = p0[i] + c0, l1 = p1[i] + c1;
        op[r] = 1.0f / (1.0f + expf(l0 - l1));
      }
    }
  }
}

// ======================= launch =======================
extern "C" void kernel_launch(void* const* d_in, const int* in_sizes, int n_in,
                              void* d_out, int out_size, void* d_ws, size_t ws_size,
                              hipStream_t stream) {
  const float* x       = (const float*)d_in[0];
  const int*   src     = (const int*)d_in[1];
  const int*   dst     = (const int*)d_in[2];
  const int*   pos_src = (const int*)d_in[3];
  const int*   pos_dst = (const int*)d_in[4];
  const int*   neg_src = (const int*)d_in[5];
  const int*   neg_dst = (const int*)d_in[6];
  const float* Ws0 = (const float*)d_in[7],  *Wn0 = (const float*)d_in[8],  *b0 = (const float*)d_in[9];
  const float* Ws1 = (const float*)d_in[10], *Wn1 = (const float*)d_in[11], *b1 = (const float*)d_in[12];
  const float* Ws2 = (const float*)d_in[13], *Wn2 = (const float*)d_in[14], *b2 = (const float*)d_in[15];
  const float* Wp0 = (const float*)d_in[16], *bp0 = (const float*)d_in[17];
  const float* Wp1 = (const float*)d_in[18], *bp1 = (const float*)d_in[19];
  const float* Wp2 = (const float*)d_in[20], *bp2 = (const float*)d_in[21];
  const int N = in_sizes[0] / D;
  const int E = in_sizes[1];
  const int P = in_sizes[3];
  float* outp = (float*)d_out;

  char* ws = (char*)d_ws;
  size_t off = 0;
  auto alloc = [&](size_t bytes) -> void* {
    void* p = ws + off;
    off += (bytes + 255) & ~(size_t)255;
    return p;
  };
  ushort* xb    = (ushort*)alloc((size_t)N * D * 2);
  ushort* h1    = (ushort*)alloc((size_t)N * D * 2);
  ushort* h2    = (ushort*)alloc((size_t)N * D * 2);
  ushort* BpL0  = (ushort*)alloc(256 * D * 2);
  ushort* BpL1  = (ushort*)alloc(256 * D * 2);
  ushort* BpL2  = (ushort*)alloc(256 * D * 2);
  ushort* BpP0  = (ushort*)alloc(128 * D * 2);
  ushort* BpP1  = (ushort*)alloc(128 * D * 2);
  int*    cnt     = (int*)alloc((size_t)(N + 64) * 4);   // counts + spillc
  int*    csrc    = (int*)alloc((size_t)N * SLOTS * 4);  // padded slots (12.8MB)
  int*    spill_d = (int*)alloc((size_t)SPILL_CAP * 4);
  int*    spill_s = (int*)alloc((size_t)SPILL_CAP * 4);
  int*    spillc  = cnt + N;
  (void)ws_size; (void)n_in; (void)out_size;

  const float pscale = 8.0f / (float)N;
  const int CB = 96;                           // blocks per part (fill)
  const int CE = (E + CB - 1) / CB;            // edges per chunk

  // --- one-pass padded CSR fill + conv/pack (fused, independent halves) ---
  hipMemsetAsync(cnt, 0, (size_t)(N + 64) * 4, stream);
  int n8 = N * D / 8;
  int cb = (n8 + 255) / 256;
  k_fill_conv<<<768 + cb + 512, 256, 0, stream>>>(
      src, dst, E, cnt, csrc, spillc, spill_d, spill_s, pscale, CE,
      x, xb, n8, cb,
      Ws0, Wn0, Ws1, Wn1, Ws2, Wn2, Wp0, Wp1,
      BpL0, BpL1, BpL2, BpP0, BpP1);

  int gemb = (N + 31) / 32;
  k_sage_fused<<<gemb, 128, 0, stream>>>(xb, cnt, csrc, spillc, spill_d, spill_s,
                                         BpL0, b0, h1, N, 1);
  k_sage_fused<<<gemb, 128, 0, stream>>>(h1, cnt, csrc, spillc, spill_d, spill_s,
                                         BpL1, b1, h2, N, 1);
  k_sage_fused<<<gemb, 128, 0, stream>>>(h2, cnt, csrc, spillc, spill_d, spill_s,
                                         BpL2, b2, xb, N, 0);

  int pb = (P + 63) / 64;
  k_predict_mfma<<<2 * pb, 256, 0, stream>>>(xb, pos_src, pos_dst, neg_src, neg_dst,
                                             BpP0, bp0, BpP1, bp1, Wp2, bp2, outp, P, pb);
}

// Round 11
// 435.073 us; speedup vs baseline: 1.3019x; 1.3019x over previous
//
#include <hip/hip_runtime.h>
#include <cstdint>
#include <cstddef>
#include <cmath>

#define D 128

typedef short bf16x8 __attribute__((ext_vector_type(8)));
typedef float f32x4 __attribute__((ext_vector_type(4)));

__device__ __forceinline__ ushort f2b(float f) {
  uint x = __float_as_uint(f);
  uint r = ((x >> 16) & 1u) + 0x7fffu;   // round-to-nearest-even
  return (ushort)((x + r) >> 16);
}
__device__ __forceinline__ float b2f(ushort u) {
  return __uint_as_float(((uint)u) << 16);
}

// global -> LDS direct DMA, 16B per lane; HW writes lane l at lds_base + l*16
__device__ __forceinline__ void gl2lds16(const void* g, void* l) {
  __builtin_amdgcn_global_load_lds(
      (__attribute__((address_space(1))) void*)const_cast<void*>(g),
      (__attribute__((address_space(3))) void*)l, 16, 0, 0);
}

// ========== fused CSR degree (XCD-partitioned) + fp32->bf16 conv + pack ======
// blocks [0,768): partitioned degree (compact 50KB atomic range per partition;
// r7-vs-r9 A/B: partitioned beats single-pass scattered atomics by ~30us).
// [768,768+cb): x conversion. Rest: weight pack. All independent -> overlap.
__global__ __launch_bounds__(256) void k_degree_conv(
    const int* __restrict__ dst, int E, int* __restrict__ deg, float scale, int CE,
    const float* __restrict__ in, ushort* __restrict__ outx, int n8, int cb,
    const float* __restrict__ Ws0, const float* __restrict__ Wn0,
    const float* __restrict__ Ws1, const float* __restrict__ Wn1,
    const float* __restrict__ Ws2, const float* __restrict__ Wn2,
    const float* __restrict__ Wp0, const float* __restrict__ Wp1,
    ushort* __restrict__ BpL0, ushort* __restrict__ BpL1, ushort* __restrict__ BpL2,
    ushort* __restrict__ BpP0, ushort* __restrict__ BpP1) {
  int b = blockIdx.x;
  if (b < 768) {
    int part = b & 7, chunk = b >> 3;
    long base = (long)chunk * CE;
    for (int i = threadIdx.x; i < CE; i += 256) {
      long e = base + i;
      if (e < E) {
        int d = dst[e];
        int p = (int)((float)d * scale); if (p > 7) p = 7;
        if (p == part) atomicAdd(&deg[d], 1);
      }
    }
    return;
  }
  int b2 = b - 768;
  if (b2 < cb) {
    int i = b2 * 256 + threadIdx.x;
    if (i >= n8) return;
    float4 a = ((const float4*)in)[i * 2];
    float4 c = ((const float4*)in)[i * 2 + 1];
    ushort4 o0 = {f2b(a.x), f2b(a.y), f2b(a.z), f2b(a.w)};
    ushort4 o1 = {f2b(c.x), f2b(c.y), f2b(c.z), f2b(c.w)};
    ((ushort4*)outx)[i * 2] = o0;
    ((ushort4*)outx)[i * 2 + 1] = o1;
    return;
  }
  int o = (b2 - cb) * 256 + threadIdx.x;   // total 131072
  const float *W0, *W1; ushort* outp; int rel;
  if (o < 32768)       { W0 = Ws0; W1 = Wn0; outp = BpL0; rel = o; }
  else if (o < 65536)  { W0 = Ws1; W1 = Wn1; outp = BpL1; rel = o - 32768; }
  else if (o < 98304)  { W0 = Ws2; W1 = Wn2; outp = BpL2; rel = o - 65536; }
  else if (o < 114688) { W0 = Wp0; W1 = Wp0; outp = BpP0; rel = o - 98304; }
  else                 { W0 = Wp1; W1 = Wp1; outp = BpP1; rel = o - 114688; }
  int j = rel & 7, lane = (rel >> 3) & 63, t = (rel >> 9) & 7, ks = rel >> 12;
  int k = ks * 32 + ((lane >> 4) * 8) + j;
  int n = t * 16 + (lane & 15);
  const float* W = (k < 128) ? W0 : W1;
  int kk = (k < 128) ? k : k - 128;
  outp[rel] = f2b(W[(size_t)kk * D + n]);
}

// fill stays XCD-partitioned: csrc scatter-writes stay L2-local.
__global__ __launch_bounds__(256) void k_fill_p(const int* __restrict__ src,
    const int* __restrict__ dst, int E, int* __restrict__ cursor,
    int* __restrict__ csrc, float scale, int CE) {
  int part = blockIdx.x & 7, chunk = blockIdx.x >> 3;
  long base = (long)chunk * CE;
  for (int i = threadIdx.x; i < CE; i += 256) {
    long e = base + i;
    if (e < E) {
      int d = dst[e];
      int p = (int)((float)d * scale); if (p > 7) p = 7;
      if (p == part) {
        int s = src[e];
        int pos = atomicAdd(&cursor[d], 1);
        csrc[pos] = s;
      }
    }
  }
}

#define SCAN_T 256
#define SCAN_E 4
#define SCAN_CHUNK (SCAN_T * SCAN_E)

__global__ void k_scan_partial(const int* __restrict__ deg, int n, int* __restrict__ part) {
  __shared__ int s[SCAN_T];
  int base = blockIdx.x * SCAN_CHUNK;
  int sum = 0;
  for (int i = 0; i < SCAN_E; ++i) {
    int idx = base + (int)threadIdx.x * SCAN_E + i;
    if (idx < n) sum += deg[idx];
  }
  s[threadIdx.x] = sum; __syncthreads();
  for (int ofs = SCAN_T / 2; ofs > 0; ofs >>= 1) {
    if ((int)threadIdx.x < ofs) s[threadIdx.x] += s[threadIdx.x + ofs];
    __syncthreads();
  }
  if (threadIdx.x == 0) part[blockIdx.x] = s[0];
}

// scan_final with self-computed block base (folds the old k_scan_part_ex).
__global__ void k_scan_final(const int* __restrict__ deg, int n, const int* __restrict__ part,
                             int nb, int* __restrict__ rowptr, int* __restrict__ cursor, int E) {
  __shared__ int s[SCAN_T];
  __shared__ int pbase;
  {
    int v = 0;
    for (int t = (int)threadIdx.x; t < (int)blockIdx.x; t += SCAN_T) v += part[t];
    s[threadIdx.x] = v; __syncthreads();
    for (int ofs = SCAN_T / 2; ofs > 0; ofs >>= 1) {
      if ((int)threadIdx.x < ofs) s[threadIdx.x] += s[threadIdx.x + ofs];
      __syncthreads();
    }
    if (threadIdx.x == 0) pbase = s[0];
    __syncthreads();
  }
  int base = blockIdx.x * SCAN_CHUNK;
  int v[SCAN_E]; int local = 0;
  for (int i = 0; i < SCAN_E; ++i) {
    int idx = base + (int)threadIdx.x * SCAN_E + i;
    v[i] = (idx < n) ? deg[idx] : 0;
    local += v[i];
  }
  s[threadIdx.x] = local; __syncthreads();
  for (int ofs = 1; ofs < SCAN_T; ofs <<= 1) {
    int t = ((int)threadIdx.x >= ofs) ? s[threadIdx.x - ofs] : 0;
    __syncthreads();
    s[threadIdx.x] += t;
    __syncthreads();
  }
  int run = pbase + s[threadIdx.x] - local;  // exclusive prefix
  for (int i = 0; i < SCAN_E; ++i) {
    int idx = base + (int)threadIdx.x * SCAN_E + i;
    if (idx < n) { rowptr[idx] = run; cursor[idx] = run; }
    run += v[i];
  }
  if (blockIdx.x == 0 && threadIdx.x == 0) rowptr[n] = E;
}

// ======================= fused aggregate + SAGE GEMM =======================
// r9 proven version (61.5-62us band): (128,4), plain stores, rowptr + dense
// csrc (padded-CSR r10 lesson: +9.6MB streaming working set -> L2 thrash ->
// out-line write-allocate churn, FETCH+WRITE double explosion. Keep the
// streaming working set minimal; L2 residency of out lines is the economy).
#define SMS 136
__global__ __launch_bounds__(128, 4) void k_sage_fused(
    const ushort* __restrict__ A, const int* __restrict__ rowptr,
    const int* __restrict__ csrc, const ushort* __restrict__ Bp,
    const float* __restrict__ bias, ushort* __restrict__ out, int N, int do_relu) {
  __shared__ __align__(16) ushort smean[2][16][SMS];   // 8704 B
  int tid = threadIdx.x, wave = tid >> 6, lane = tid & 63;
  int m = lane & 15, kg = lane >> 4;        // MFMA roles
  int g = kg, sub = m;                      // gather roles: 4 groups of 16
  int gb = g << 4;                          // group base lane
  int row0 = (blockIdx.x * 2 + wave) * 16;  // this wave's 16-row tile
  uint hbo = (uint)(sub * 16);              // byte offset of this lane's 16B slice

  // ---- phase A: rowptr + edge-index prefetch ----
  int node0 = row0 + g * 4;
  int rpv = 0;
  if (sub < 5) { int ix = node0 + sub; if (ix > N) ix = N; rpv = rowptr[ix]; }
  int beg[4], dgf[4], dd[4];
  #pragma unroll
  for (int j = 0; j < 4; ++j) {
    beg[j] = __shfl(rpv, gb + j);
    int endj = __shfl(rpv, gb + j + 1);
    dgf[j] = endj - beg[j];
    dd[j] = dgf[j] < 16 ? dgf[j] : 16;
  }
  int idxv[4];
  #pragma unroll
  for (int j = 0; j < 4; ++j) {
    int i = beg[j] + sub;
    idxv[j] = (sub < dgf[j]) ? csrc[i] : 0;
  }

  // ---- phase B: unroll-4 gather, unconditional 16-load clusters ----
  float f[4][8];
  #pragma unroll
  for (int j = 0; j < 4; ++j)
    #pragma unroll
    for (int q = 0; q < 8; ++q) f[j][q] = 0.f;

  int maxdd = dd[0];
  if (dd[1] > maxdd) maxdd = dd[1];
  if (dd[2] > maxdd) maxdd = dd[2];
  if (dd[3] > maxdd) maxdd = dd[3];

  uint off[4][4];
  #pragma unroll
  for (int j = 0; j < 4; ++j)
    #pragma unroll
    for (int k = 0; k < 4; ++k)
      off[j][k] = hbo + ((uint)__shfl(idxv[j], gb + k) << 8);

  #pragma unroll 1
  for (int e = 0; e < maxdd; e += 4) {
    bf16x8 r[4][4];
    #pragma unroll
    for (int j = 0; j < 4; ++j)
      #pragma unroll
      for (int k = 0; k < 4; ++k)
        r[j][k] = *(const bf16x8*)((const char*)A + off[j][k]);
    __builtin_amdgcn_sched_barrier(0);
    #pragma unroll
    for (int j = 0; j < 4; ++j)
      #pragma unroll
      for (int k = 0; k < 4; ++k) {
        int sl = e + 4 + k; sl = (sl > 15) ? 15 : sl;
        off[j][k] = hbo + ((uint)__shfl(idxv[j], gb + sl) << 8);
      }
    __builtin_amdgcn_sched_barrier(0);
    #pragma unroll
    for (int j = 0; j < 4; ++j) {
      #pragma unroll
      for (int k = 0; k < 4; ++k) {
        float w = (e + k < dd[j]) ? 1.0f : 0.0f;
        #pragma unroll
        for (int q = 0; q < 8; ++q) f[j][q] += w * b2f((ushort)r[j][k][q]);
      }
    }
  }
  // rare deg>16 tail
  #pragma unroll
  for (int j = 0; j < 4; ++j) {
    int endj = beg[j] + dgf[j];
    for (int i = beg[j] + 16; i < endj; ++i) {
      int s = csrc[i];
      bf16x8 v = *(const bf16x8*)((const char*)A + (hbo + ((uint)s << 8)));
      #pragma unroll
      for (int q = 0; q < 8; ++q) f[j][q] += b2f((ushort)v[q]);
    }
  }
  #pragma unroll
  for (int j = 0; j < 4; ++j) {
    float inv = (dgf[j] > 0) ? (1.0f / (float)dgf[j]) : 0.0f;
    bf16x8 o;
    #pragma unroll
    for (int q = 0; q < 8; ++q) o[q] = (short)f2b(f[j][q] * inv);
    *(bf16x8*)&smean[wave][g * 4 + j][sub * 8] = o;
  }
  asm volatile("s_waitcnt lgkmcnt(0)" ::: "memory");
  __builtin_amdgcn_sched_barrier(0);

  // ---- MFMA phase ----
  int ar = row0 + m; if (ar >= N) ar = N - 1;
  const ushort* a_self = A + (size_t)ar * D + kg * 8;
  f32x4 acc[8];
  #pragma unroll
  for (int t = 0; t < 8; ++t) acc[t] = f32x4{0.f, 0.f, 0.f, 0.f};
  #pragma unroll
  for (int ks = 0; ks < 8; ++ks) {
    bf16x8 af = (ks < 4) ? *(const bf16x8*)(a_self + ks * 32)
                         : *(const bf16x8*)&smean[wave][m][(ks - 4) * 32 + kg * 8];
    const ushort* bb = Bp + (size_t)ks * 4096 + lane * 8;
    #pragma unroll
    for (int t = 0; t < 8; ++t)
      acc[t] = __builtin_amdgcn_mfma_f32_16x16x32_bf16(af, *(const bf16x8*)(bb + t * 512), acc[t], 0, 0, 0);
  }
  #pragma unroll
  for (int t = 0; t < 8; ++t) {
    int c = t * 16 + m;
    float bv = bias[c];
    #pragma unroll
    for (int i = 0; i < 4; ++i) {
      int r = row0 + kg * 4 + i;
      float v = acc[t][i] + bv;
      if (do_relu) v = fmaxf(v, 0.f);
      if (r < N) out[(size_t)r * D + c] = f2b(v);
    }
  }
}

// ======================= fused predictor MLP (DMA-staged gathers) ==============
__global__ __launch_bounds__(256, 5) void k_predict_mfma(
    const ushort* __restrict__ h,
    const int* __restrict__ ps, const int* __restrict__ pd,
    const int* __restrict__ ns, const int* __restrict__ nd,
    const ushort* __restrict__ Bp0, const float* __restrict__ bp0,
    const ushort* __restrict__ Bp1, const float* __restrict__ bp1,
    const float* __restrict__ Wp2, const float* __restrict__ bp2,
    float* __restrict__ outp, int P, int pb) {
  __shared__ __align__(1024) ushort slab[4][4096];  // 8KB/wave: hs @0, hd @4KB
  int bi = blockIdx.x;
  const int* sidx; const int* didx; float* op;
  if (bi >= pb) { sidx = ns; didx = nd; op = outp + P; bi -= pb; }
  else          { sidx = ps; didx = pd; op = outp; }
  int tid = threadIdx.x;
  int wave = tid >> 6, lane = tid & 63;
  int m = lane & 15, kg = lane >> 4;
  int pair0 = bi * 64 + wave * 16;
  int prow = pair0 + m; int pr = (prow < P) ? prow : P - 1;
  int si = sidx[pr], di = didx[pr];    // lane m holds pair m (kg-duplicated)
  char* sl = (char*)&slab[wave][0];

  // ---- stage: instr q covers rows q*4+(lane>>4); lane l writes LDS at +l*16.
  // source slice = (l&15) ^ (row&7)  => LDS slot c of row r holds slice c^(r&7)
  {
    int rsub = lane >> 4;
    #pragma unroll
    for (int q = 0; q < 4; ++q) {
      int rr = q * 4 + rsub;
      int ir = __shfl(si, rr);
      const char* g = (const char*)h + ((size_t)(uint)ir << 8)
                      + (uint)((((lane & 15) ^ (rr & 7)) << 4));
      gl2lds16(g, sl + (q << 10));
    }
    #pragma unroll
    for (int q = 0; q < 4; ++q) {
      int rr = q * 4 + rsub;
      int ir = __shfl(di, rr);
      const char* g = (const char*)h + ((size_t)(uint)ir << 8)
                      + (uint)((((lane & 15) ^ (rr & 7)) << 4));
      gl2lds16(g, sl + 4096 + (q << 10));
    }
  }
  __syncthreads();   // compiler drains vmcnt(0) before barrier (m97 semantics)

  f32x4 acc[8];
  #pragma unroll
  for (int t = 0; t < 8; ++t) acc[t] = f32x4{0.f, 0.f, 0.f, 0.f};
  // ---- GEMM1: z = hs*hd ; acc = z @ Wp0 (swizzled LDS reads) ----
  #pragma unroll
  for (int ks = 0; ks < 4; ++ks) {
    int slot = (ks * 4 + kg) ^ (m & 7);
    const char* rbase = sl + m * 256 + slot * 16;
    bf16x8 as8 = *(const bf16x8*)rbase;
    bf16x8 ad8 = *(const bf16x8*)(rbase + 4096);
    bf16x8 af;
    #pragma unroll
    for (int j = 0; j < 8; ++j) {
      float p = b2f((ushort)as8[j]) * b2f((ushort)ad8[j]);
      af[j] = (short)f2b(p);
    }
    const ushort* bb = Bp0 + (size_t)ks * 4096 + lane * 8;
    #pragma unroll
    for (int t = 0; t < 8; ++t)
      acc[t] = __builtin_amdgcn_mfma_f32_16x16x32_bf16(af, *(const bf16x8*)(bb + t * 512), acc[t], 0, 0, 0);
  }
  // ---- epilogue1: relu(acc + bp0) -> z1p (overlays consumed hs region) ----
  ushort* zp = (ushort*)sl;
  #pragma unroll
  for (int t = 0; t < 8; ++t) {
    int c = t * 16 + m;
    float bv = bp0[c];
    int ks2 = c >> 5, kg2 = (c >> 3) & 3, j2 = c & 7;
    #pragma unroll
    for (int i = 0; i < 4; ++i) {
      float v = fmaxf(acc[t][i] + bv, 0.f);
      int l2 = kg2 * 16 + kg * 4 + i;     // consumer lane
      zp[(ks2 * 64 + l2) * 8 + j2] = f2b(v);
    }
  }
  // wave-local handoff (slab written and read by THIS wave only)
  asm volatile("s_waitcnt lgkmcnt(0)" ::: "memory");
  __builtin_amdgcn_sched_barrier(0);
  // ---- GEMM2: acc = z1 @ Wp1 ----
  #pragma unroll
  for (int t = 0; t < 8; ++t) acc[t] = f32x4{0.f, 0.f, 0.f, 0.f};
  #pragma unroll
  for (int ks = 0; ks < 4; ++ks) {
    bf16x8 af = *(const bf16x8*)(zp + (ks * 64 + lane) * 8);
    const ushort* bb = Bp1 + (size_t)ks * 4096 + lane * 8;
    #pragma unroll
    for (int t = 0; t < 8; ++t)
      acc[t] = __builtin_amdgcn_mfma_f32_16x16x32_bf16(af, *(const bf16x8*)(bb + t * 512), acc[t], 0, 0, 0);
  }
  // ---- final: z2 = relu(acc + bp1); logits = z2 @ Wp2 + bp2; sigmoid ----
  float p0[4] = {0.f, 0.f, 0.f, 0.f}, p1[4] = {0.f, 0.f, 0.f, 0.f};
  #pragma unroll
  for (int t = 0; t < 8; ++t) {
    int c = t * 16 + m;
    float bv = bp1[c];
    float wa = Wp2[(size_t)c * 2], wb = Wp2[(size_t)c * 2 + 1];
    #pragma unroll
    for (int i = 0; i < 4; ++i) {
      float z = fmaxf(acc[t][i] + bv, 0.f);
      p0[i] += z * wa;
      p1[i] += z * wb;
    }
  }
  #pragma unroll
  for (int msk = 1; msk <= 8; msk <<= 1) {
    #pragma unroll
    for (int i = 0; i < 4; ++i) {
      p0[i] += __shfl_xor(p0[i], msk);
      p1[i] += __shfl_xor(p1[i], msk);
    }
  }
  if (m == 0) {
    float c0 = bp2[0], c1 = bp2[1];
    #pragma unroll
    for (int i = 0; i < 4; ++i) {
      int r = pair0 + kg * 4 + i;
      if (r < P) {
        float l0 = p0[i] + c0, l1 = p1[i] + c1;
        op[r] = 1.0f / (1.0f + expf(l0 - l1));
      }
    }
  }
}

// ======================= launch =======================
extern "C" void kernel_launch(void* const* d_in, const int* in_sizes, int n_in,
                              void* d_out, int out_size, void* d_ws, size_t ws_size,
                              hipStream_t stream) {
  const float* x       = (const float*)d_in[0];
  const int*   src     = (const int*)d_in[1];
  const int*   dst     = (const int*)d_in[2];
  const int*   pos_src = (const int*)d_in[3];
  const int*   pos_dst = (const int*)d_in[4];
  const int*   neg_src = (const int*)d_in[5];
  const int*   neg_dst = (const int*)d_in[6];
  const float* Ws0 = (const float*)d_in[7],  *Wn0 = (const float*)d_in[8],  *b0 = (const float*)d_in[9];
  const float* Ws1 = (const float*)d_in[10], *Wn1 = (const float*)d_in[11], *b1 = (const float*)d_in[12];
  const float* Ws2 = (const float*)d_in[13], *Wn2 = (const float*)d_in[14], *b2 = (const float*)d_in[15];
  const float* Wp0 = (const float*)d_in[16], *bp0 = (const float*)d_in[17];
  const float* Wp1 = (const float*)d_in[18], *bp1 = (const float*)d_in[19];
  const float* Wp2 = (const float*)d_in[20], *bp2 = (const float*)d_in[21];
  const int N = in_sizes[0] / D;
  const int E = in_sizes[1];
  const int P = in_sizes[3];
  float* outp = (float*)d_out;

  char* ws = (char*)d_ws;
  size_t off = 0;
  auto alloc = [&](size_t bytes) -> void* {
    void* p = ws + off;
    off += (bytes + 255) & ~(size_t)255;
    return p;
  };
  ushort* xb    = (ushort*)alloc((size_t)N * D * 2);
  ushort* h1    = (ushort*)alloc((size_t)N * D * 2);
  ushort* h2    = (ushort*)alloc((size_t)N * D * 2);
  ushort* BpL0  = (ushort*)alloc(256 * D * 2);
  ushort* BpL1  = (ushort*)alloc(256 * D * 2);
  ushort* BpL2  = (ushort*)alloc(256 * D * 2);
  ushort* BpP0  = (ushort*)alloc(128 * D * 2);
  ushort* BpP1  = (ushort*)alloc(128 * D * 2);
  int*    deg    = (int*)alloc((size_t)N * 4);
  int*    rowptr = (int*)alloc((size_t)(N + 1) * 4);
  int*    cursor = (int*)alloc((size_t)N * 4);
  int*    part   = (int*)alloc(4096);
  int*    csrc   = (int*)alloc((size_t)E * 4);
  (void)ws_size; (void)n_in; (void)out_size;

  const float pscale = 8.0f / (float)N;
  const int CB = 96;                           // blocks per part
  const int CE = (E + CB - 1) / CB;            // edges per chunk

  // --- CSR degree (partitioned, fused w/ conv+pack) ---
  hipMemsetAsync(deg, 0, (size_t)N * 4, stream);
  int n8 = N * D / 8;
  int cb = (n8 + 255) / 256;
  k_degree_conv<<<8 * CB + cb + 512, 256, 0, stream>>>(
      dst, E, deg, pscale, CE,
      x, xb, n8, cb,
      Ws0, Wn0, Ws1, Wn1, Ws2, Wn2, Wp0, Wp1,
      BpL0, BpL1, BpL2, BpP0, BpP1);

  int nb = (N + SCAN_CHUNK - 1) / SCAN_CHUNK;
  k_scan_partial<<<nb, SCAN_T, 0, stream>>>(deg, N, part);
  k_scan_final<<<nb, SCAN_T, 0, stream>>>(deg, N, part, nb, rowptr, cursor, E);
  k_fill_p<<<8 * CB, 256, 0, stream>>>(src, dst, E, cursor, csrc, pscale, CE);

  int gemb = (N + 31) / 32;
  k_sage_fused<<<gemb, 128, 0, stream>>>(xb, rowptr, csrc, BpL0, b0, h1, N, 1);
  k_sage_fused<<<gemb, 128, 0, stream>>>(h1, rowptr, csrc, BpL1, b1, h2, N, 1);
  k_sage_fused<<<gemb, 128, 0, stream>>>(h2, rowptr, csrc, BpL2, b2, xb, N, 0);

  int pb = (P + 63) / 64;
  k_predict_mfma<<<2 * pb, 256, 0, stream>>>(xb, pos_src, pos_dst, neg_src, neg_dst,
                                             BpP0, bp0, BpP1, bp1, Wp2, bp2, outp, P, pb);
}

// Round 12
// 428.860 us; speedup vs baseline: 1.3207x; 1.0145x over previous
//
#include <hip/hip_runtime.h>
#include <cstdint>
#include <cstddef>
#include <cmath>

#define D 128
#define PARTS 4      // dst-range partitions for edge passes (r12: 8->4 halves
                     // redundant chunk reads; 100KB atomic range still L2-local)
#define CHUNKS 192   // edge chunks; grid = PARTS*CHUNKS = 768 (same as before)

typedef short bf16x8 __attribute__((ext_vector_type(8)));
typedef float f32x4 __attribute__((ext_vector_type(4)));

__device__ __forceinline__ ushort f2b(float f) {
  uint x = __float_as_uint(f);
  uint r = ((x >> 16) & 1u) + 0x7fffu;   // round-to-nearest-even
  return (ushort)((x + r) >> 16);
}
__device__ __forceinline__ float b2f(ushort u) {
  return __uint_as_float(((uint)u) << 16);
}

// global -> LDS direct DMA, 16B per lane; HW writes lane l at lds_base + l*16
__device__ __forceinline__ void gl2lds16(const void* g, void* l) {
  __builtin_amdgcn_global_load_lds(
      (__attribute__((address_space(1))) void*)const_cast<void*>(g),
      (__attribute__((address_space(3))) void*)l, 16, 0, 0);
}

// ========== fused CSR degree (range-partitioned) + fp32->bf16 conv + pack ====
// blocks [0,768): partitioned degree -- partition p owns d in [pN/4,(p+1)N/4);
// each edge chunk is read by 4 blocks (was 8): half the redundant streaming
// reads, atomic range per partition 100KB (still L2-resident -- the locality
// mechanism the r7/r9 A/B showed is worth ~30us).
// [768,768+cb): x conversion. Rest: weight pack. All independent -> overlap.
__global__ __launch_bounds__(256) void k_degree_conv(
    const int* __restrict__ dst, int E, int* __restrict__ deg, float scale, int CE,
    const float* __restrict__ in, ushort* __restrict__ outx, int n8, int cb,
    const float* __restrict__ Ws0, const float* __restrict__ Wn0,
    const float* __restrict__ Ws1, const float* __restrict__ Wn1,
    const float* __restrict__ Ws2, const float* __restrict__ Wn2,
    const float* __restrict__ Wp0, const float* __restrict__ Wp1,
    ushort* __restrict__ BpL0, ushort* __restrict__ BpL1, ushort* __restrict__ BpL2,
    ushort* __restrict__ BpP0, ushort* __restrict__ BpP1) {
  int b = blockIdx.x;
  if (b < PARTS * CHUNKS) {
    int part = b & (PARTS - 1), chunk = b >> 2;
    long base = (long)chunk * CE;
    for (int i = threadIdx.x; i < CE; i += 256) {
      long e = base + i;
      if (e < E) {
        int d = dst[e];
        int p = (int)((float)d * scale); if (p > PARTS - 1) p = PARTS - 1;
        if (p == part) atomicAdd(&deg[d], 1);
      }
    }
    return;
  }
  int b2 = b - PARTS * CHUNKS;
  if (b2 < cb) {
    int i = b2 * 256 + threadIdx.x;
    if (i >= n8) return;
    float4 a = ((const float4*)in)[i * 2];
    float4 c = ((const float4*)in)[i * 2 + 1];
    ushort4 o0 = {f2b(a.x), f2b(a.y), f2b(a.z), f2b(a.w)};
    ushort4 o1 = {f2b(c.x), f2b(c.y), f2b(c.z), f2b(c.w)};
    ((ushort4*)outx)[i * 2] = o0;
    ((ushort4*)outx)[i * 2 + 1] = o1;
    return;
  }
  int o = (b2 - cb) * 256 + threadIdx.x;   // total 131072
  const float *W0, *W1; ushort* outp; int rel;
  if (o < 32768)       { W0 = Ws0; W1 = Wn0; outp = BpL0; rel = o; }
  else if (o < 65536)  { W0 = Ws1; W1 = Wn1; outp = BpL1; rel = o - 32768; }
  else if (o < 98304)  { W0 = Ws2; W1 = Wn2; outp = BpL2; rel = o - 65536; }
  else if (o < 114688) { W0 = Wp0; W1 = Wp0; outp = BpP0; rel = o - 98304; }
  else                 { W0 = Wp1; W1 = Wp1; outp = BpP1; rel = o - 114688; }
  int j = rel & 7, lane = (rel >> 3) & 63, t = (rel >> 9) & 7, ks = rel >> 12;
  int k = ks * 32 + ((lane >> 4) * 8) + j;
  int n = t * 16 + (lane & 15);
  const float* W = (k < 128) ? W0 : W1;
  int kk = (k < 128) ? k : k - 128;
  outp[rel] = f2b(W[(size_t)kk * D + n]);
}

// fill: same 4-partition decomposition (halved redundant reads, L2-local
// cursor atomics + csrc scatter-writes).
__global__ __launch_bounds__(256) void k_fill_p(const int* __restrict__ src,
    const int* __restrict__ dst, int E, int* __restrict__ cursor,
    int* __restrict__ csrc, float scale, int CE) {
  int part = blockIdx.x & (PARTS - 1), chunk = blockIdx.x >> 2;
  long base = (long)chunk * CE;
  for (int i = threadIdx.x; i < CE; i += 256) {
    long e = base + i;
    if (e < E) {
      int d = dst[e];
      int p = (int)((float)d * scale); if (p > PARTS - 1) p = PARTS - 1;
      if (p == part) {
        int s = src[e];
        int pos = atomicAdd(&cursor[d], 1);
        csrc[pos] = s;
      }
    }
  }
}

#define SCAN_T 256
#define SCAN_E 4
#define SCAN_CHUNK (SCAN_T * SCAN_E)

__global__ void k_scan_partial(const int* __restrict__ deg, int n, int* __restrict__ part) {
  __shared__ int s[SCAN_T];
  int base = blockIdx.x * SCAN_CHUNK;
  int sum = 0;
  for (int i = 0; i < SCAN_E; ++i) {
    int idx = base + (int)threadIdx.x * SCAN_E + i;
    if (idx < n) sum += deg[idx];
  }
  s[threadIdx.x] = sum; __syncthreads();
  for (int ofs = SCAN_T / 2; ofs > 0; ofs >>= 1) {
    if ((int)threadIdx.x < ofs) s[threadIdx.x] += s[threadIdx.x + ofs];
    __syncthreads();
  }
  if (threadIdx.x == 0) part[blockIdx.x] = s[0];
}

// scan_final with self-computed block base (folds the old k_scan_part_ex).
__global__ void k_scan_final(const int* __restrict__ deg, int n, const int* __restrict__ part,
                             int nb, int* __restrict__ rowptr, int* __restrict__ cursor, int E) {
  __shared__ int s[SCAN_T];
  __shared__ int pbase;
  {
    int v = 0;
    for (int t = (int)threadIdx.x; t < (int)blockIdx.x; t += SCAN_T) v += part[t];
    s[threadIdx.x] = v; __syncthreads();
    for (int ofs = SCAN_T / 2; ofs > 0; ofs >>= 1) {
      if ((int)threadIdx.x < ofs) s[threadIdx.x] += s[threadIdx.x + ofs];
      __syncthreads();
    }
    if (threadIdx.x == 0) pbase = s[0];
    __syncthreads();
  }
  int base = blockIdx.x * SCAN_CHUNK;
  int v[SCAN_E]; int local = 0;
  for (int i = 0; i < SCAN_E; ++i) {
    int idx = base + (int)threadIdx.x * SCAN_E + i;
    v[i] = (idx < n) ? deg[idx] : 0;
    local += v[i];
  }
  s[threadIdx.x] = local; __syncthreads();
  for (int ofs = 1; ofs < SCAN_T; ofs <<= 1) {
    int t = ((int)threadIdx.x >= ofs) ? s[threadIdx.x - ofs] : 0;
    __syncthreads();
    s[threadIdx.x] += t;
    __syncthreads();
  }
  int run = pbase + s[threadIdx.x] - local;  // exclusive prefix
  for (int i = 0; i < SCAN_E; ++i) {
    int idx = base + (int)threadIdx.x * SCAN_E + i;
    if (idx < n) { rowptr[idx] = run; cursor[idx] = run; }
    run += v[i];
  }
  if (blockIdx.x == 0 && threadIdx.x == 0) rowptr[n] = E;
}

// ======================= fused aggregate + SAGE GEMM =======================
// r9/r11 proven version (61.5-62.6us band): (128,4), plain stores, rowptr +
// dense csrc. Session rules encoded: no nt-stores (r8: 10x write inflation),
// no launch-bounds squeeze (r8: shrinks load cluster), no extra streaming
// working set (r10: L2 thrash -> out-line write-allocate churn).
#define SMS 136
__global__ __launch_bounds__(128, 4) void k_sage_fused(
    const ushort* __restrict__ A, const int* __restrict__ rowptr,
    const int* __restrict__ csrc, const ushort* __restrict__ Bp,
    const float* __restrict__ bias, ushort* __restrict__ out, int N, int do_relu) {
  __shared__ __align__(16) ushort smean[2][16][SMS];   // 8704 B
  int tid = threadIdx.x, wave = tid >> 6, lane = tid & 63;
  int m = lane & 15, kg = lane >> 4;        // MFMA roles
  int g = kg, sub = m;                      // gather roles: 4 groups of 16
  int gb = g << 4;                          // group base lane
  int row0 = (blockIdx.x * 2 + wave) * 16;  // this wave's 16-row tile
  uint hbo = (uint)(sub * 16);              // byte offset of this lane's 16B slice

  // ---- phase A: rowptr + edge-index prefetch ----
  int node0 = row0 + g * 4;
  int rpv = 0;
  if (sub < 5) { int ix = node0 + sub; if (ix > N) ix = N; rpv = rowptr[ix]; }
  int beg[4], dgf[4], dd[4];
  #pragma unroll
  for (int j = 0; j < 4; ++j) {
    beg[j] = __shfl(rpv, gb + j);
    int endj = __shfl(rpv, gb + j + 1);
    dgf[j] = endj - beg[j];
    dd[j] = dgf[j] < 16 ? dgf[j] : 16;
  }
  int idxv[4];
  #pragma unroll
  for (int j = 0; j < 4; ++j) {
    int i = beg[j] + sub;
    idxv[j] = (sub < dgf[j]) ? csrc[i] : 0;
  }

  // ---- phase B: unroll-4 gather, unconditional 16-load clusters ----
  float f[4][8];
  #pragma unroll
  for (int j = 0; j < 4; ++j)
    #pragma unroll
    for (int q = 0; q < 8; ++q) f[j][q] = 0.f;

  int maxdd = dd[0];
  if (dd[1] > maxdd) maxdd = dd[1];
  if (dd[2] > maxdd) maxdd = dd[2];
  if (dd[3] > maxdd) maxdd = dd[3];

  uint off[4][4];
  #pragma unroll
  for (int j = 0; j < 4; ++j)
    #pragma unroll
    for (int k = 0; k < 4; ++k)
      off[j][k] = hbo + ((uint)__shfl(idxv[j], gb + k) << 8);

  #pragma unroll 1
  for (int e = 0; e < maxdd; e += 4) {
    bf16x8 r[4][4];
    #pragma unroll
    for (int j = 0; j < 4; ++j)
      #pragma unroll
      for (int k = 0; k < 4; ++k)
        r[j][k] = *(const bf16x8*)((const char*)A + off[j][k]);
    __builtin_amdgcn_sched_barrier(0);
    #pragma unroll
    for (int j = 0; j < 4; ++j)
      #pragma unroll
      for (int k = 0; k < 4; ++k) {
        int sl = e + 4 + k; sl = (sl > 15) ? 15 : sl;
        off[j][k] = hbo + ((uint)__shfl(idxv[j], gb + sl) << 8);
      }
    __builtin_amdgcn_sched_barrier(0);
    #pragma unroll
    for (int j = 0; j < 4; ++j) {
      #pragma unroll
      for (int k = 0; k < 4; ++k) {
        float w = (e + k < dd[j]) ? 1.0f : 0.0f;
        #pragma unroll
        for (int q = 0; q < 8; ++q) f[j][q] += w * b2f((ushort)r[j][k][q]);
      }
    }
  }
  // rare deg>16 tail
  #pragma unroll
  for (int j = 0; j < 4; ++j) {
    int endj = beg[j] + dgf[j];
    for (int i = beg[j] + 16; i < endj; ++i) {
      int s = csrc[i];
      bf16x8 v = *(const bf16x8*)((const char*)A + (hbo + ((uint)s << 8)));
      #pragma unroll
      for (int q = 0; q < 8; ++q) f[j][q] += b2f((ushort)v[q]);
    }
  }
  #pragma unroll
  for (int j = 0; j < 4; ++j) {
    float inv = (dgf[j] > 0) ? (1.0f / (float)dgf[j]) : 0.0f;
    bf16x8 o;
    #pragma unroll
    for (int q = 0; q < 8; ++q) o[q] = (short)f2b(f[j][q] * inv);
    *(bf16x8*)&smean[wave][g * 4 + j][sub * 8] = o;
  }
  asm volatile("s_waitcnt lgkmcnt(0)" ::: "memory");
  __builtin_amdgcn_sched_barrier(0);

  // ---- MFMA phase ----
  int ar = row0 + m; if (ar >= N) ar = N - 1;
  const ushort* a_self = A + (size_t)ar * D + kg * 8;
  f32x4 acc[8];
  #pragma unroll
  for (int t = 0; t < 8; ++t) acc[t] = f32x4{0.f, 0.f, 0.f, 0.f};
  #pragma unroll
  for (int ks = 0; ks < 8; ++ks) {
    bf16x8 af = (ks < 4) ? *(const bf16x8*)(a_self + ks * 32)
                         : *(const bf16x8*)&smean[wave][m][(ks - 4) * 32 + kg * 8];
    const ushort* bb = Bp + (size_t)ks * 4096 + lane * 8;
    #pragma unroll
    for (int t = 0; t < 8; ++t)
      acc[t] = __builtin_amdgcn_mfma_f32_16x16x32_bf16(af, *(const bf16x8*)(bb + t * 512), acc[t], 0, 0, 0);
  }
  #pragma unroll
  for (int t = 0; t < 8; ++t) {
    int c = t * 16 + m;
    float bv = bias[c];
    #pragma unroll
    for (int i = 0; i < 4; ++i) {
      int r = row0 + kg * 4 + i;
      float v = acc[t][i] + bv;
      if (do_relu) v = fmaxf(v, 0.f);
      if (r < N) out[(size_t)r * D + c] = f2b(v);
    }
  }
}

// ======================= fused predictor MLP (DMA-staged gathers) ==============
__global__ __launch_bounds__(256, 5) void k_predict_mfma(
    const ushort* __restrict__ h,
    const int* __restrict__ ps, const int* __restrict__ pd,
    const int* __restrict__ ns, const int* __restrict__ nd,
    const ushort* __restrict__ Bp0, const float* __restrict__ bp0,
    const ushort* __restrict__ Bp1, const float* __restrict__ bp1,
    const float* __restrict__ Wp2, const float* __restrict__ bp2,
    float* __restrict__ outp, int P, int pb) {
  __shared__ __align__(1024) ushort slab[4][4096];  // 8KB/wave: hs @0, hd @4KB
  int bi = blockIdx.x;
  const int* sidx; const int* didx; float* op;
  if (bi >= pb) { sidx = ns; didx = nd; op = outp + P; bi -= pb; }
  else          { sidx = ps; didx = pd; op = outp; }
  int tid = threadIdx.x;
  int wave = tid >> 6, lane = tid & 63;
  int m = lane & 15, kg = lane >> 4;
  int pair0 = bi * 64 + wave * 16;
  int prow = pair0 + m; int pr = (prow < P) ? prow : P - 1;
  int si = sidx[pr], di = didx[pr];    // lane m holds pair m (kg-duplicated)
  char* sl = (char*)&slab[wave][0];

  // ---- stage: instr q covers rows q*4+(lane>>4); lane l writes LDS at +l*16.
  // source slice = (l&15) ^ (row&7)  => LDS slot c of row r holds slice c^(r&7)
  {
    int rsub = lane >> 4;
    #pragma unroll
    for (int q = 0; q < 4; ++q) {
      int rr = q * 4 + rsub;
      int ir = __shfl(si, rr);
      const char* g = (const char*)h + ((size_t)(uint)ir << 8)
                      + (uint)((((lane & 15) ^ (rr & 7)) << 4));
      gl2lds16(g, sl + (q << 10));
    }
    #pragma unroll
    for (int q = 0; q < 4; ++q) {
      int rr = q * 4 + rsub;
      int ir = __shfl(di, rr);
      const char* g = (const char*)h + ((size_t)(uint)ir << 8)
                      + (uint)((((lane & 15) ^ (rr & 7)) << 4));
      gl2lds16(g, sl + 4096 + (q << 10));
    }
  }
  __syncthreads();   // compiler drains vmcnt(0) before barrier (m97 semantics)

  f32x4 acc[8];
  #pragma unroll
  for (int t = 0; t < 8; ++t) acc[t] = f32x4{0.f, 0.f, 0.f, 0.f};
  // ---- GEMM1: z = hs*hd ; acc = z @ Wp0 (swizzled LDS reads) ----
  #pragma unroll
  for (int ks = 0; ks < 4; ++ks) {
    int slot = (ks * 4 + kg) ^ (m & 7);
    const char* rbase = sl + m * 256 + slot * 16;
    bf16x8 as8 = *(const bf16x8*)rbase;
    bf16x8 ad8 = *(const bf16x8*)(rbase + 4096);
    bf16x8 af;
    #pragma unroll
    for (int j = 0; j < 8; ++j) {
      float p = b2f((ushort)as8[j]) * b2f((ushort)ad8[j]);
      af[j] = (short)f2b(p);
    }
    const ushort* bb = Bp0 + (size_t)ks * 4096 + lane * 8;
    #pragma unroll
    for (int t = 0; t < 8; ++t)
      acc[t] = __builtin_amdgcn_mfma_f32_16x16x32_bf16(af, *(const bf16x8*)(bb + t * 512), acc[t], 0, 0, 0);
  }
  // ---- epilogue1: relu(acc + bp0) -> z1p (overlays consumed hs region) ----
  ushort* zp = (ushort*)sl;
  #pragma unroll
  for (int t = 0; t < 8; ++t) {
    int c = t * 16 + m;
    float bv = bp0[c];
    int ks2 = c >> 5, kg2 = (c >> 3) & 3, j2 = c & 7;
    #pragma unroll
    for (int i = 0; i < 4; ++i) {
      float v = fmaxf(acc[t][i] + bv, 0.f);
      int l2 = kg2 * 16 + kg * 4 + i;     // consumer lane
      zp[(ks2 * 64 + l2) * 8 + j2] = f2b(v);
    }
  }
  // wave-local handoff (slab written and read by THIS wave only)
  asm volatile("s_waitcnt lgkmcnt(0)" ::: "memory");
  __builtin_amdgcn_sched_barrier(0);
  // ---- GEMM2: acc = z1 @ Wp1 ----
  #pragma unroll
  for (int t = 0; t < 8; ++t) acc[t] = f32x4{0.f, 0.f, 0.f, 0.f};
  #pragma unroll
  for (int ks = 0; ks < 4; ++ks) {
    bf16x8 af = *(const bf16x8*)(zp + (ks * 64 + lane) * 8);
    const ushort* bb = Bp1 + (size_t)ks * 4096 + lane * 8;
    #pragma unroll
    for (int t = 0; t < 8; ++t)
      acc[t] = __builtin_amdgcn_mfma_f32_16x16x32_bf16(af, *(const bf16x8*)(bb + t * 512), acc[t], 0, 0, 0);
  }
  // ---- final: z2 = relu(acc + bp1); logits = z2 @ Wp2 + bp2; sigmoid ----
  float p0[4] = {0.f, 0.f, 0.f, 0.f}, p1[4] = {0.f, 0.f, 0.f, 0.f};
  #pragma unroll
  for (int t = 0; t < 8; ++t) {
    int c = t * 16 + m;
    float bv = bp1[c];
    float wa = Wp2[(size_t)c * 2], wb = Wp2[(size_t)c * 2 + 1];
    #pragma unroll
    for (int i = 0; i < 4; ++i) {
      float z = fmaxf(acc[t][i] + bv, 0.f);
      p0[i] += z * wa;
      p1[i] += z * wb;
    }
  }
  #pragma unroll
  for (int msk = 1; msk <= 8; msk <<= 1) {
    #pragma unroll
    for (int i = 0; i < 4; ++i) {
      p0[i] += __shfl_xor(p0[i], msk);
      p1[i] += __shfl_xor(p1[i], msk);
    }
  }
  if (m == 0) {
    float c0 = bp2[0], c1 = bp2[1];
    #pragma unroll
    for (int i = 0; i < 4; ++i) {
      int r = pair0 + kg * 4 + i;
      if (r < P) {
        float l0 = p0[i] + c0, l1 = p1[i] + c1;
        op[r] = 1.0f / (1.0f + expf(l0 - l1));
      }
    }
  }
}

// ======================= launch =======================
extern "C" void kernel_launch(void* const* d_in, const int* in_sizes, int n_in,
                              void* d_out, int out_size, void* d_ws, size_t ws_size,
                              hipStream_t stream) {
  const float* x       = (const float*)d_in[0];
  const int*   src     = (const int*)d_in[1];
  const int*   dst     = (const int*)d_in[2];
  const int*   pos_src = (const int*)d_in[3];
  const int*   pos_dst = (const int*)d_in[4];
  const int*   neg_src = (const int*)d_in[5];
  const int*   neg_dst = (const int*)d_in[6];
  const float* Ws0 = (const float*)d_in[7],  *Wn0 = (const float*)d_in[8],  *b0 = (const float*)d_in[9];
  const float* Ws1 = (const float*)d_in[10], *Wn1 = (const float*)d_in[11], *b1 = (const float*)d_in[12];
  const float* Ws2 = (const float*)d_in[13], *Wn2 = (const float*)d_in[14], *b2 = (const float*)d_in[15];
  const float* Wp0 = (const float*)d_in[16], *bp0 = (const float*)d_in[17];
  const float* Wp1 = (const float*)d_in[18], *bp1 = (const float*)d_in[19];
  const float* Wp2 = (const float*)d_in[20], *bp2 = (const float*)d_in[21];
  const int N = in_sizes[0] / D;
  const int E = in_sizes[1];
  const int P = in_sizes[3];
  float* outp = (float*)d_out;

  char* ws = (char*)d_ws;
  size_t off = 0;
  auto alloc = [&](size_t bytes) -> void* {
    void* p = ws + off;
    off += (bytes + 255) & ~(size_t)255;
    return p;
  };
  ushort* xb    = (ushort*)alloc((size_t)N * D * 2);
  ushort* h1    = (ushort*)alloc((size_t)N * D * 2);
  ushort* h2    = (ushort*)alloc((size_t)N * D * 2);
  ushort* BpL0  = (ushort*)alloc(256 * D * 2);
  ushort* BpL1  = (ushort*)alloc(256 * D * 2);
  ushort* BpL2  = (ushort*)alloc(256 * D * 2);
  ushort* BpP0  = (ushort*)alloc(128 * D * 2);
  ushort* BpP1  = (ushort*)alloc(128 * D * 2);
  int*    deg    = (int*)alloc((size_t)N * 4);
  int*    rowptr = (int*)alloc((size_t)(N + 1) * 4);
  int*    cursor = (int*)alloc((size_t)N * 4);
  int*    part   = (int*)alloc(4096);
  int*    csrc   = (int*)alloc((size_t)E * 4);
  (void)ws_size; (void)n_in; (void)out_size;

  const float pscale = (float)PARTS / (float)N;
  const int CE = (E + CHUNKS - 1) / CHUNKS;    // edges per chunk

  // --- CSR degree (4-partitioned, fused w/ conv+pack) ---
  hipMemsetAsync(deg, 0, (size_t)N * 4, stream);
  int n8 = N * D / 8;
  int cb = (n8 + 255) / 256;
  k_degree_conv<<<PARTS * CHUNKS + cb + 512, 256, 0, stream>>>(
      dst, E, deg, pscale, CE,
      x, xb, n8, cb,
      Ws0, Wn0, Ws1, Wn1, Ws2, Wn2, Wp0, Wp1,
      BpL0, BpL1, BpL2, BpP0, BpP1);

  int nb = (N + SCAN_CHUNK - 1) / SCAN_CHUNK;
  k_scan_partial<<<nb, SCAN_T, 0, stream>>>(deg, N, part);
  k_scan_final<<<nb, SCAN_T, 0, stream>>>(deg, N, part, nb, rowptr, cursor, E);
  k_fill_p<<<PARTS * CHUNKS, 256, 0, stream>>>(src, dst, E, cursor, csrc, pscale, CE);

  int gemb = (N + 31) / 32;
  k_sage_fused<<<gemb, 128, 0, stream>>>(xb, rowptr, csrc, BpL0, b0, h1, N, 1);
  k_sage_fused<<<gemb, 128, 0, stream>>>(h1, rowptr, csrc, BpL1, b1, h2, N, 1);
  k_sage_fused<<<gemb, 128, 0, stream>>>(h2, rowptr, csrc, BpL2, b2, xb, N, 0);

  int pb = (P + 63) / 64;
  k_predict_mfma<<<2 * pb, 256, 0, stream>>>(xb, pos_src, pos_dst, neg_src, neg_dst,
                                             BpP0, bp0, BpP1, bp1, Wp2, bp2, outp, P, pb);
}